// Round 5
// baseline (401.692 us; speedup 1.0000x reference)
//
#include <hip/hip_runtime.h>

// ShiftingLayer: out = zeros(H,W); out[i + trunc(wr[i,j]), j + trunc(wc[i,j])] = x[i,j]
// (OOB targets dropped). H=4096, W=8192, fp32.
//
// R4 post-mortem: dur_us = fixed ~245us harness floor + kernel-sum (1:1
// tracking across sessions). copy(2-stream) and scan(pure read) each ran at
// ~3.5 TB/s while rocclr fillBuffer hit 6.8 TB/s in the same graph -> the
// cap is OUR kernel geometry (8192 one-shot blocks, block-owned ranges),
// not stream mix (R3 falsified batching/occupancy, R4 falsified mix).
//
// R5 structure:
//   1. hipMemcpyAsync D2D out<-x  (driver-tuned blit; harness-blessed G9)
//   2. scan_kernel: grid-stride, 2048 blocks (G11 geometry), 16 chunks/thr
//      in two 8-deep per-stream batches; worklist-append nonzero chunks
//      (empty for bench inputs)
//   3. fix_zero, fix_scatter over worklist (empty -> immediate exit);
//      all zeroes before all scatters preserves general-case semantics.
//
// Prev-session lesson: __builtin_nontemporal_store regressed streaming
// stores ~10% at identical traffic — plain stores only.

constexpr int H = 4096;
constexpr int W = 8192;                         // 2^13
constexpr long long TOTAL  = (long long)H * W;  // 33,554,432
constexpr long long NCHUNK = TOTAL / 4;         // 8,388,608 float4 chunks
constexpr int BLOCK = 256;

constexpr int SCAN_GRID  = 2048;                // G11: ~8 blocks/CU, grid-stride
constexpr int SCAN_BATCH = 8;                   // chunks per batch per stream
constexpr int SCAN_ITERS = 2;                   // 16 chunks/thread total
// 2048*256 threads * 16 chunks = 8,388,608 = NCHUNK exactly.

typedef float vf4 __attribute__((ext_vector_type(4)));

// ---- worklist path -------------------------------------------------------

__global__ __launch_bounds__(64) void init_ws_kernel(unsigned* __restrict__ ws) {
    if (threadIdx.x == 0) ws[0] = 0u;           // d_ws is poisoned 0xAA each call
}

// Phase 2: pure read of wr/wc; worklist-append chunks with any nonzero shift.
// Grid-stride geometry (consecutive threads -> consecutive chunks; batches
// stride 8MB apart, m13-style).
__global__ __launch_bounds__(BLOCK) void scan_kernel(
    const float* __restrict__ wr,
    const float* __restrict__ wc,
    unsigned* __restrict__ ws_count,
    unsigned* __restrict__ ws_list)
{
    const long long stride = (long long)gridDim.x * blockDim.x;     // 524288
    const long long t0     = (long long)blockIdx.x * blockDim.x + threadIdx.x;

    #pragma unroll
    for (int it = 0; it < SCAN_ITERS; ++it) {
        long long c[SCAN_BATCH];
        vf4 rv[SCAN_BATCH], cv[SCAN_BATCH];

        #pragma unroll
        for (int j = 0; j < SCAN_BATCH; ++j) {
            c[j]  = t0 + (long long)(it * SCAN_BATCH + j) * stride;
            rv[j] = *reinterpret_cast<const vf4*>(wr + c[j] * 4);
        }
        #pragma unroll
        for (int j = 0; j < SCAN_BATCH; ++j) {
            cv[j] = *reinterpret_cast<const vf4*>(wc + c[j] * 4);
        }

        #pragma unroll
        for (int j = 0; j < SCAN_BATCH; ++j) {
            // C float->int cast truncates toward zero == jnp.trunc + astype(int32)
            const int m = ((int)rv[j].x | (int)rv[j].y | (int)rv[j].z | (int)rv[j].w |
                           (int)cv[j].x | (int)cv[j].y | (int)cv[j].z | (int)cv[j].w);
            if (m != 0) {
                unsigned slot = atomicAdd(ws_count, 1u);   // device-scope default
                ws_list[slot] = (unsigned)c[j];
            }
        }
    }
}

// Phase 3: zero the source positions of shifted elements (out[i,j] was set
// to x[i,j] by the copy; reference drops those values).
__global__ __launch_bounds__(BLOCK) void fix_zero_kernel(
    const float* __restrict__ wr,
    const float* __restrict__ wc,
    float* __restrict__ out,
    const unsigned* __restrict__ ws_count,
    const unsigned* __restrict__ ws_list)
{
    const unsigned count  = ws_count[0];
    const unsigned stride = gridDim.x * blockDim.x;
    for (unsigned i = blockIdx.x * blockDim.x + threadIdx.x; i < count; i += stride) {
        const long long base = (long long)ws_list[i] * 4;
        const vf4 rv = *reinterpret_cast<const vf4*>(wr + base);
        const vf4 cv = *reinterpret_cast<const vf4*>(wc + base);
        if (((int)rv.x | (int)cv.x) != 0) out[base + 0] = 0.0f;
        if (((int)rv.y | (int)cv.y) != 0) out[base + 1] = 0.0f;
        if (((int)rv.z | (int)cv.z) != 0) out[base + 2] = 0.0f;
        if (((int)rv.w | (int)cv.w) != 0) out[base + 3] = 0.0f;
    }
}

// Phase 4: scatter shifted elements to their in-bounds targets.
__global__ __launch_bounds__(BLOCK) void fix_scatter_kernel(
    const float* __restrict__ x,
    const float* __restrict__ wr,
    const float* __restrict__ wc,
    float* __restrict__ out,
    const unsigned* __restrict__ ws_count,
    const unsigned* __restrict__ ws_list)
{
    const unsigned count  = ws_count[0];
    const unsigned stride = gridDim.x * blockDim.x;
    for (unsigned i = blockIdx.x * blockDim.x + threadIdx.x; i < count; i += stride) {
        const long long base = (long long)ws_list[i] * 4;
        const int row = (int)(base >> 13);
        const int col = (int)(base & (W - 1));

        const vf4 xv = *reinterpret_cast<const vf4*>(x  + base);
        const vf4 rv = *reinterpret_cast<const vf4*>(wr + base);
        const vf4 cv = *reinterpret_cast<const vf4*>(wc + base);

        int rs, cs, tr, tc;
        rs = (int)rv.x; cs = (int)cv.x;
        if ((rs | cs) != 0) { tr = row + rs; tc = col + 0 + cs;
            if ((unsigned)tr < (unsigned)H && (unsigned)tc < (unsigned)W)
                out[(long long)tr * W + tc] = xv.x; }
        rs = (int)rv.y; cs = (int)cv.y;
        if ((rs | cs) != 0) { tr = row + rs; tc = col + 1 + cs;
            if ((unsigned)tr < (unsigned)H && (unsigned)tc < (unsigned)W)
                out[(long long)tr * W + tc] = xv.y; }
        rs = (int)rv.z; cs = (int)cv.z;
        if ((rs | cs) != 0) { tr = row + rs; tc = col + 2 + cs;
            if ((unsigned)tr < (unsigned)H && (unsigned)tc < (unsigned)W)
                out[(long long)tr * W + tc] = xv.z; }
        rs = (int)rv.w; cs = (int)cv.w;
        if ((rs | cs) != 0) { tr = row + rs; tc = col + 3 + cs;
            if ((unsigned)tr < (unsigned)H && (unsigned)tc < (unsigned)W)
                out[(long long)tr * W + tc] = xv.w; }
    }
}

// ---- fallback path (if d_ws too small): zero + full scatter --------------

__global__ __launch_bounds__(BLOCK) void zero_out_kernel(float* __restrict__ out) {
    long long tid = (long long)blockIdx.x * blockDim.x + threadIdx.x;
    vf4 z = {0.f, 0.f, 0.f, 0.f};
    *reinterpret_cast<vf4*>(out + tid * 4) = z;
}

__global__ __launch_bounds__(BLOCK) void shift_scatter_kernel(
    const float* __restrict__ x,
    const float* __restrict__ wr,
    const float* __restrict__ wc,
    float* __restrict__ out)
{
    long long tid  = (long long)blockIdx.x * blockDim.x + threadIdx.x;
    long long base = tid * 4;
    int row = (int)(base >> 13);
    int col = (int)(base & (W - 1));

    const vf4 xv = *reinterpret_cast<const vf4*>(x  + base);
    const vf4 rv = *reinterpret_cast<const vf4*>(wr + base);
    const vf4 cv = *reinterpret_cast<const vf4*>(wc + base);

    int rs0 = (int)rv.x, rs1 = (int)rv.y, rs2 = (int)rv.z, rs3 = (int)rv.w;
    int cs0 = (int)cv.x, cs1 = (int)cv.y, cs2 = (int)cv.z, cs3 = (int)cv.w;

    if (((rs0 | rs1 | rs2 | rs3) | (cs0 | cs1 | cs2 | cs3)) == 0) {
        *reinterpret_cast<vf4*>(out + base) = xv;
        return;
    }
    int tr, tc;
    tr = row + rs0; tc = col + 0 + cs0;
    if ((unsigned)tr < (unsigned)H && (unsigned)tc < (unsigned)W)
        out[(long long)tr * W + tc] = xv.x;
    tr = row + rs1; tc = col + 1 + cs1;
    if ((unsigned)tr < (unsigned)H && (unsigned)tc < (unsigned)W)
        out[(long long)tr * W + tc] = xv.y;
    tr = row + rs2; tc = col + 2 + cs2;
    if ((unsigned)tr < (unsigned)H && (unsigned)tc < (unsigned)W)
        out[(long long)tr * W + tc] = xv.z;
    tr = row + rs3; tc = col + 3 + cs3;
    if ((unsigned)tr < (unsigned)H && (unsigned)tc < (unsigned)W)
        out[(long long)tr * W + tc] = xv.w;
}

// ---- launch --------------------------------------------------------------

extern "C" void kernel_launch(void* const* d_in, const int* in_sizes, int n_in,
                              void* d_out, int out_size, void* d_ws, size_t ws_size,
                              hipStream_t stream) {
    const float* x  = (const float*)d_in[0];
    const float* wr = (const float*)d_in[1];
    const float* wc = (const float*)d_in[2];
    float* out = (float*)d_out;

    // worklist layout in d_ws: [0] counter (unsigned), [16..] chunk indices
    const size_t ws_needed = 16 + (size_t)NCHUNK * sizeof(unsigned);

    if (ws_size >= ws_needed) {
        unsigned* ws_count = (unsigned*)d_ws;
        unsigned* ws_list  = (unsigned*)((char*)d_ws + 16);

        init_ws_kernel<<<1, 64, 0, stream>>>(ws_count);
        // Phase 1: out = x via the driver's tuned D2D path (G9-blessed).
        hipMemcpyAsync(out, x, (size_t)TOTAL * sizeof(float),
                       hipMemcpyDeviceToDevice, stream);
        scan_kernel<<<SCAN_GRID, BLOCK, 0, stream>>>(wr, wc, ws_count, ws_list);
        fix_zero_kernel<<<256, BLOCK, 0, stream>>>(wr, wc, out,
                                                   ws_count, ws_list);
        fix_scatter_kernel<<<256, BLOCK, 0, stream>>>(x, wr, wc, out,
                                                      ws_count, ws_list);
    } else {
        const int grid = (int)(NCHUNK / BLOCK);             // 32768 blocks
        zero_out_kernel<<<grid, BLOCK, 0, stream>>>(out);
        shift_scatter_kernel<<<grid, BLOCK, 0, stream>>>(x, wr, wc, out);
    }
}

// Round 6
// 364.644 us; speedup vs baseline: 1.1016x; 1.1016x over previous
//
#include <hip/hip_runtime.h>

// ShiftingLayer: out = zeros(H,W); out[i + trunc(wr[i,j]), j + trunc(wc[i,j])] = x[i,j]
// (OOB targets dropped). H=4096, W=8192, fp32.
//
// MODEL (R0-R5 evidence): the read-request path caps at ~3.0-3.15 TB/s
// (latency x per-CU outstanding), insensitive to batching (R3), occupancy
// 37-74% (R3), stream mix (R4), grid geometry / driver copy (R5); writes
// sustain 6.8 TB/s (fillBuffer). m13's 6.29 copy = 3.15R+3.15W, same cap.
// 384 MB of reads is irreducible -> fused single-pass (write overlapped
// under the read stream) is the optimal structure: 141us today, 131us best.
//
// R6 probe (last untested lever): NONTEMPORAL LOADS on x/wr/wc — skip
// L2/LLC allocation for the streaming reads (LLC hits measurably don't
// speed timing here, so allocation is pure queue/latency overhead).
// NT stores regressed 10% (different mechanism) — stores stay plain.
// Structure = R0 fused exactly (CPT=4, 8192 one-shot blocks) for clean A/B
// vs today's 140-142us measurement of the same structure.
// Null result (+-3us) => read cap is HW; declare roofline.

constexpr int H = 4096;
constexpr int W = 8192;                         // 2^13
constexpr long long TOTAL  = (long long)H * W;  // 33,554,432
constexpr long long NCHUNK = TOTAL / 4;         // 8,388,608 float4 chunks
constexpr int BLOCK = 256;
constexpr int CPT   = 4;                        // chunks per thread

typedef float vf4 __attribute__((ext_vector_type(4)));

// ---- worklist path -------------------------------------------------------

__global__ __launch_bounds__(64) void init_ws_kernel(unsigned* __restrict__ ws) {
    if (threadIdx.x == 0) ws[0] = 0u;           // d_ws is poisoned 0xAA each call
}

__global__ __launch_bounds__(BLOCK) void fused_place_kernel(
    const float* __restrict__ x,
    const float* __restrict__ wr,
    const float* __restrict__ wc,
    float* __restrict__ out,
    unsigned* __restrict__ ws_count,
    unsigned* __restrict__ ws_list)
{
    const long long chunk0 = (long long)blockIdx.x * (BLOCK * CPT) + threadIdx.x;

    vf4 xv[CPT], rv[CPT], cv[CPT];
    #pragma unroll
    for (int u = 0; u < CPT; ++u) {
        const long long base = (chunk0 + (long long)u * BLOCK) * 4;
        xv[u] = __builtin_nontemporal_load(reinterpret_cast<const vf4*>(x  + base));
        rv[u] = __builtin_nontemporal_load(reinterpret_cast<const vf4*>(wr + base));
        cv[u] = __builtin_nontemporal_load(reinterpret_cast<const vf4*>(wc + base));
    }

    #pragma unroll
    for (int u = 0; u < CPT; ++u) {
        const long long chunk = chunk0 + (long long)u * BLOCK;
        const long long base  = chunk * 4;

        // C float->int cast truncates toward zero == jnp.trunc + astype(int32)
        int rs0 = (int)rv[u].x, rs1 = (int)rv[u].y,
            rs2 = (int)rv[u].z, rs3 = (int)rv[u].w;
        int cs0 = (int)cv[u].x, cs1 = (int)cv[u].y,
            cs2 = (int)cv[u].z, cs3 = (int)cv[u].w;

        if (((rs0 | rs1 | rs2 | rs3) | (cs0 | cs1 | cs2 | cs3)) == 0) {
            *reinterpret_cast<vf4*>(out + base) = xv[u];
        } else {
            vf4 ov;
            ov.x = ((rs0 | cs0) == 0) ? xv[u].x : 0.0f;
            ov.y = ((rs1 | cs1) == 0) ? xv[u].y : 0.0f;
            ov.z = ((rs2 | cs2) == 0) ? xv[u].z : 0.0f;
            ov.w = ((rs3 | cs3) == 0) ? xv[u].w : 0.0f;
            *reinterpret_cast<vf4*>(out + base) = ov;
            unsigned slot = atomicAdd(ws_count, 1u);   // device-scope default
            ws_list[slot] = (unsigned)chunk;
        }
    }
}

__global__ __launch_bounds__(BLOCK) void worklist_scatter_kernel(
    const float* __restrict__ x,
    const float* __restrict__ wr,
    const float* __restrict__ wc,
    float* __restrict__ out,
    const unsigned* __restrict__ ws_count,
    const unsigned* __restrict__ ws_list)
{
    const unsigned count  = ws_count[0];
    const unsigned stride = gridDim.x * blockDim.x;
    for (unsigned i = blockIdx.x * blockDim.x + threadIdx.x; i < count; i += stride) {
        long long base = (long long)ws_list[i] * 4;
        int row = (int)(base >> 13);
        int col = (int)(base & (W - 1));

        const vf4 xv = *reinterpret_cast<const vf4*>(x  + base);
        const vf4 rv = *reinterpret_cast<const vf4*>(wr + base);
        const vf4 cv = *reinterpret_cast<const vf4*>(wc + base);

        int rs, cs, tr, tc;
        rs = (int)rv.x; cs = (int)cv.x;
        if ((rs | cs) != 0) { tr = row + rs; tc = col + 0 + cs;
            if ((unsigned)tr < (unsigned)H && (unsigned)tc < (unsigned)W)
                out[(long long)tr * W + tc] = xv.x; }
        rs = (int)rv.y; cs = (int)cv.y;
        if ((rs | cs) != 0) { tr = row + rs; tc = col + 1 + cs;
            if ((unsigned)tr < (unsigned)H && (unsigned)tc < (unsigned)W)
                out[(long long)tr * W + tc] = xv.y; }
        rs = (int)rv.z; cs = (int)cv.z;
        if ((rs | cs) != 0) { tr = row + rs; tc = col + 2 + cs;
            if ((unsigned)tr < (unsigned)H && (unsigned)tc < (unsigned)W)
                out[(long long)tr * W + tc] = xv.z; }
        rs = (int)rv.w; cs = (int)cv.w;
        if ((rs | cs) != 0) { tr = row + rs; tc = col + 3 + cs;
            if ((unsigned)tr < (unsigned)H && (unsigned)tc < (unsigned)W)
                out[(long long)tr * W + tc] = xv.w; }
    }
}

// ---- fallback path (if d_ws too small): zero + full scatter --------------

__global__ __launch_bounds__(BLOCK) void zero_out_kernel(float* __restrict__ out) {
    long long tid = (long long)blockIdx.x * blockDim.x + threadIdx.x;
    vf4 z = {0.f, 0.f, 0.f, 0.f};
    *reinterpret_cast<vf4*>(out + tid * 4) = z;
}

__global__ __launch_bounds__(BLOCK) void shift_scatter_kernel(
    const float* __restrict__ x,
    const float* __restrict__ wr,
    const float* __restrict__ wc,
    float* __restrict__ out)
{
    long long tid  = (long long)blockIdx.x * blockDim.x + threadIdx.x;
    long long base = tid * 4;
    int row = (int)(base >> 13);
    int col = (int)(base & (W - 1));

    const vf4 xv = *reinterpret_cast<const vf4*>(x  + base);
    const vf4 rv = *reinterpret_cast<const vf4*>(wr + base);
    const vf4 cv = *reinterpret_cast<const vf4*>(wc + base);

    int rs0 = (int)rv.x, rs1 = (int)rv.y, rs2 = (int)rv.z, rs3 = (int)rv.w;
    int cs0 = (int)cv.x, cs1 = (int)cv.y, cs2 = (int)cv.z, cs3 = (int)cv.w;

    if (((rs0 | rs1 | rs2 | rs3) | (cs0 | cs1 | cs2 | cs3)) == 0) {
        *reinterpret_cast<vf4*>(out + base) = xv;
        return;
    }
    int tr, tc;
    tr = row + rs0; tc = col + 0 + cs0;
    if ((unsigned)tr < (unsigned)H && (unsigned)tc < (unsigned)W)
        out[(long long)tr * W + tc] = xv.x;
    tr = row + rs1; tc = col + 1 + cs1;
    if ((unsigned)tr < (unsigned)H && (unsigned)tc < (unsigned)W)
        out[(long long)tr * W + tc] = xv.y;
    tr = row + rs2; tc = col + 2 + cs2;
    if ((unsigned)tr < (unsigned)H && (unsigned)tc < (unsigned)W)
        out[(long long)tr * W + tc] = xv.z;
    tr = row + rs3; tc = col + 3 + cs3;
    if ((unsigned)tr < (unsigned)H && (unsigned)tc < (unsigned)W)
        out[(long long)tr * W + tc] = xv.w;
}

// ---- launch --------------------------------------------------------------

extern "C" void kernel_launch(void* const* d_in, const int* in_sizes, int n_in,
                              void* d_out, int out_size, void* d_ws, size_t ws_size,
                              hipStream_t stream) {
    const float* x  = (const float*)d_in[0];
    const float* wr = (const float*)d_in[1];
    const float* wc = (const float*)d_in[2];
    float* out = (float*)d_out;

    // worklist layout in d_ws: [0] counter (unsigned), [16..] chunk indices
    const size_t ws_needed = 16 + (size_t)NCHUNK * sizeof(unsigned);

    if (ws_size >= ws_needed) {
        unsigned* ws_count = (unsigned*)d_ws;
        unsigned* ws_list  = (unsigned*)((char*)d_ws + 16);
        const int grid = (int)(NCHUNK / (BLOCK * CPT));     // 8192 blocks
        init_ws_kernel<<<1, 64, 0, stream>>>(ws_count);
        fused_place_kernel<<<grid, BLOCK, 0, stream>>>(x, wr, wc, out,
                                                       ws_count, ws_list);
        worklist_scatter_kernel<<<1024, BLOCK, 0, stream>>>(x, wr, wc, out,
                                                            ws_count, ws_list);
    } else {
        const int grid = (int)(NCHUNK / BLOCK);             // 32768 blocks
        zero_out_kernel<<<grid, BLOCK, 0, stream>>>(out);
        shift_scatter_kernel<<<grid, BLOCK, 0, stream>>>(x, wr, wc, out);
    }
}